// Round 1
// baseline (155.384 us; speedup 1.0000x reference)
//
#include <hip/hip_runtime.h>

#define IN_SZ   256
#define OUT_SZ  256
#define NNZ_C   2048
#define NB      16      // nodes per block

__global__ __launch_bounds__(256, 4)
void sparse_tp_kernel(const float* __restrict__ input,
                      const float* __restrict__ scale,
                      const int*   __restrict__ M_in,
                      const int*   __restrict__ M,
                      float*       __restrict__ out,
                      int N)
{
    __shared__ float s_in[NB * IN_SZ];       // 16 KB
    __shared__ float s_scale[NNZ_C];         // 8 KB
    __shared__ int   s_min[NNZ_C];           // 8 KB
    __shared__ int   s_seg[OUT_SZ + 1];      // ~1 KB

    const int tid  = threadIdx.x;
    const int base = blockIdx.x * NB;

    // ---- stage scale + M_in (vectorized, coalesced) ----
    {
        const float4* sc4  = reinterpret_cast<const float4*>(scale);
        const int4*   mi4  = reinterpret_cast<const int4*>(M_in);
        float4*       ssc4 = reinterpret_cast<float4*>(s_scale);
        int4*         smi4 = reinterpret_cast<int4*>(s_min);
#pragma unroll
        for (int v = tid; v < NNZ_C / 4; v += 256) {
            ssc4[v] = sc4[v];
            smi4[v] = mi4[v];
        }
    }

    // ---- stage NB input rows (vectorized, coalesced) ----
    {
        const float4* in4 = reinterpret_cast<const float4*>(input + (size_t)base * IN_SZ);
        float4*       si4 = reinterpret_cast<float4*>(s_in);
#pragma unroll
        for (int v = tid; v < NB * IN_SZ / 4; v += 256) {
            int row = v / (IN_SZ / 4);
            if (base + row < N) si4[v] = in4[v];
        }
    }

    // ---- segment starts: s_seg[j] = first k with M[k] >= j (M sorted) ----
    {
        int j  = tid;
        int lo = 0, hi = NNZ_C;
        while (lo < hi) {
            int mid = (lo + hi) >> 1;
            if (M[mid] < j) lo = mid + 1; else hi = mid;
        }
        s_seg[j] = lo;
        if (tid == 0) s_seg[OUT_SZ] = NNZ_C;
    }
    __syncthreads();

    // ---- per-thread: one output column j, NB node accumulators ----
    float acc[NB];
#pragma unroll
    for (int i = 0; i < NB; ++i) acc[i] = 0.f;

    const int j  = tid;
    const int k1 = s_seg[j + 1];
    for (int k = s_seg[j]; k < k1; ++k) {
        const float s = s_scale[k];
        const int   m = s_min[k];
#pragma unroll
        for (int i = 0; i < NB; ++i)
            acc[i] += s * s_in[i * IN_SZ + m];
    }

    // ---- coalesced store (every element written -> poison overwritten) ----
    float* orow = out + (size_t)base * OUT_SZ + j;
#pragma unroll
    for (int i = 0; i < NB; ++i) {
        if (base + i < N) orow[(size_t)i * OUT_SZ] = acc[i];
    }
}

extern "C" void kernel_launch(void* const* d_in, const int* in_sizes, int n_in,
                              void* d_out, int out_size, void* d_ws, size_t ws_size,
                              hipStream_t stream)
{
    const float* input = (const float*)d_in[0];
    const float* scale = (const float*)d_in[1];
    const int*   M_in  = (const int*)d_in[2];
    const int*   M     = (const int*)d_in[3];
    float*       out   = (float*)d_out;

    const int N = in_sizes[0] / IN_SZ;
    const int grid = (N + NB - 1) / NB;

    sparse_tp_kernel<<<grid, 256, 0, stream>>>(input, scale, M_in, M, out, N);
}

// Round 2
// 130.517 us; speedup vs baseline: 1.1905x; 1.1905x over previous
//
#include <hip/hip_runtime.h>
#include <hip/hip_bf16.h>

#define IN_SZ   256
#define OUT_SZ  256
#define NNZ_C   2048
#define NB      16      // nodes per block (fallback kernel)

typedef __attribute__((ext_vector_type(8))) short bf16x8;
typedef __attribute__((ext_vector_type(4))) float f32x4;

static __device__ __forceinline__ short f2bf(float f) {
    __hip_bfloat16 h = __float2bfloat16(f);
    return (short)__builtin_bit_cast(unsigned short, h);
}

// ---------------- W builder kernels (W^T layout: w[j][m], 256x256) ----------------

__global__ void zero_kernel(float* __restrict__ w) {
    int i = blockIdx.x * 256 + threadIdx.x;          // 64 blocks * 256 thr * 4 = 65536 f32
    ((float4*)w)[i] = (float4){0.f, 0.f, 0.f, 0.f};
}

__global__ void scatter_kernel(const float* __restrict__ scale,
                               const int* __restrict__ M_in,
                               const int* __restrict__ M,
                               float* __restrict__ w) {
    int k = blockIdx.x * 256 + threadIdx.x;
    if (k < NNZ_C) atomicAdd(&w[M[k] * IN_SZ + M_in[k]], scale[k]);
}

__global__ void cvt_kernel(const float* __restrict__ w, unsigned short* __restrict__ wb) {
    int i = blockIdx.x * 256 + threadIdx.x;          // 64 blocks: 16384 thr * 4 = 65536
    float4 v = ((const float4*)w)[i];
    ushort4 o;
    o.x = (unsigned short)f2bf(v.x);
    o.y = (unsigned short)f2bf(v.y);
    o.z = (unsigned short)f2bf(v.z);
    o.w = (unsigned short)f2bf(v.w);
    ((ushort4*)wb)[i] = o;
}

// ---------------- GEMM: out[65536x256] = input[65536x256(f32->bf16)] * W ----------------
// BM=128, BN=256(full), BK=64; 512 threads = 8 waves (2x4), wave tile 64x64.

#define BM 128
#define BK 64

__global__ __launch_bounds__(512, 2)
void gemm_kernel(const float* __restrict__ input,
                 const unsigned short* __restrict__ wbf,   // [j][m] = W^T, bf16
                 float* __restrict__ out)
{
    __shared__ unsigned short sA[BM * BK];       // 16 KB, [row][k], XOR-swizzled
    __shared__ unsigned short sB[OUT_SZ * BK];   // 32 KB, [col][k], XOR-swizzled

    const int tid  = threadIdx.x;
    const int lane = tid & 63;
    const int wid  = tid >> 6;
    const int wm   = wid >> 2;      // 0..1
    const int wn   = wid & 3;       // 0..3
    const long blockRow = (long)blockIdx.x * BM;

    f32x4 acc[4][4];
#pragma unroll
    for (int m = 0; m < 4; ++m)
#pragma unroll
        for (int n = 0; n < 4; ++n)
            acc[m][n] = (f32x4){0.f, 0.f, 0.f, 0.f};

    for (int kt = 0; kt < IN_SZ / BK; ++kt) {
        __syncthreads();
        // ---- stage A: 128 rows x 64 k, f32 -> bf16, 1024 16B chunks (2/thread) ----
#pragma unroll
        for (int it = 0; it < 2; ++it) {
            int idx = tid + it * 512;
            int row = idx >> 3, c8 = idx & 7;
            const float4* g = (const float4*)(input + (blockRow + row) * IN_SZ + kt * BK + c8 * 8);
            float4 v0 = g[0], v1 = g[1];
            bf16x8 u;
            u[0] = f2bf(v0.x); u[1] = f2bf(v0.y); u[2] = f2bf(v0.z); u[3] = f2bf(v0.w);
            u[4] = f2bf(v1.x); u[5] = f2bf(v1.y); u[6] = f2bf(v1.z); u[7] = f2bf(v1.w);
            int lb = (row * 128 + c8 * 16) ^ ((row & 7) << 4);
            *(bf16x8*)((char*)sA + lb) = u;
        }
        // ---- stage B: 256 cols x 64 k bf16, 2048 16B chunks (4/thread) ----
#pragma unroll
        for (int it = 0; it < 4; ++it) {
            int idx = tid + it * 512;
            int col = idx >> 3, k8 = idx & 7;
            bf16x8 u = *(const bf16x8*)(wbf + col * IN_SZ + kt * BK + k8 * 8);
            int lb = (col * 128 + k8 * 16) ^ ((col & 7) << 4);
            *(bf16x8*)((char*)sB + lb) = u;
        }
        __syncthreads();

        // ---- fragment loads (ds_read_b128, 2-way max bank aliasing = free) ----
        bf16x8 af[2][4], bfr[2][4];
#pragma unroll
        for (int kf = 0; kf < 2; ++kf) {
#pragma unroll
            for (int m = 0; m < 4; ++m) {
                int row  = wm * 64 + m * 16 + (lane & 15);
                int koff = kf * 32 + (lane >> 4) * 8;
                int lb = (row * 128 + koff * 2) ^ ((row & 7) << 4);
                af[kf][m] = *(const bf16x8*)((const char*)sA + lb);
            }
#pragma unroll
            for (int n = 0; n < 4; ++n) {
                int col  = wn * 64 + n * 16 + (lane & 15);
                int koff = kf * 32 + (lane >> 4) * 8;
                int lb = (col * 128 + koff * 2) ^ ((col & 7) << 4);
                bfr[kf][n] = *(const bf16x8*)((const char*)sB + lb);
            }
        }
#pragma unroll
        for (int kf = 0; kf < 2; ++kf)
#pragma unroll
            for (int m = 0; m < 4; ++m)
#pragma unroll
                for (int n = 0; n < 4; ++n)
                    acc[m][n] = __builtin_amdgcn_mfma_f32_16x16x32_bf16(
                        af[kf][m], bfr[kf][n], acc[m][n], 0, 0, 0);
    }

    // ---- epilogue: C/D layout col=lane&15, row=(lane>>4)*4+r (guide-verified) ----
#pragma unroll
    for (int m = 0; m < 4; ++m) {
        int row0 = wm * 64 + m * 16 + ((lane >> 4) << 2);
#pragma unroll
        for (int n = 0; n < 4; ++n) {
            int col = wn * 64 + n * 16 + (lane & 15);
#pragma unroll
            for (int r = 0; r < 4; ++r)
                out[(blockRow + row0 + r) * OUT_SZ + col] = acc[m][n][r];
        }
    }
}

// ---------------- fallback: round-1 sparse kernel ----------------

__global__ __launch_bounds__(256, 4)
void sparse_tp_kernel(const float* __restrict__ input,
                      const float* __restrict__ scale,
                      const int*   __restrict__ M_in,
                      const int*   __restrict__ M,
                      float*       __restrict__ out,
                      int N)
{
    __shared__ float s_in[NB * IN_SZ];
    __shared__ float s_scale[NNZ_C];
    __shared__ int   s_min[NNZ_C];
    __shared__ int   s_seg[OUT_SZ + 1];

    const int tid  = threadIdx.x;
    const int base = blockIdx.x * NB;

    {
        const float4* sc4  = reinterpret_cast<const float4*>(scale);
        const int4*   mi4  = reinterpret_cast<const int4*>(M_in);
        float4*       ssc4 = reinterpret_cast<float4*>(s_scale);
        int4*         smi4 = reinterpret_cast<int4*>(s_min);
        for (int v = tid; v < NNZ_C / 4; v += 256) { ssc4[v] = sc4[v]; smi4[v] = mi4[v]; }
    }
    {
        const float4* in4 = reinterpret_cast<const float4*>(input + (size_t)base * IN_SZ);
        float4*       si4 = reinterpret_cast<float4*>(s_in);
        for (int v = tid; v < NB * IN_SZ / 4; v += 256) {
            int row = v / (IN_SZ / 4);
            if (base + row < N) si4[v] = in4[v];
        }
    }
    {
        int j = tid, lo = 0, hi = NNZ_C;
        while (lo < hi) { int mid = (lo + hi) >> 1; if (M[mid] < j) lo = mid + 1; else hi = mid; }
        s_seg[j] = lo;
        if (tid == 0) s_seg[OUT_SZ] = NNZ_C;
    }
    __syncthreads();

    float acc[NB];
#pragma unroll
    for (int i = 0; i < NB; ++i) acc[i] = 0.f;

    const int j = tid;
    const int k1 = s_seg[j + 1];
    for (int k = s_seg[j]; k < k1; ++k) {
        const float s = s_scale[k];
        const int   m = s_min[k];
#pragma unroll
        for (int i = 0; i < NB; ++i) acc[i] += s * s_in[i * IN_SZ + m];
    }

    float* orow = out + (size_t)base * OUT_SZ + j;
#pragma unroll
    for (int i = 0; i < NB; ++i)
        if (base + i < N) orow[(size_t)i * OUT_SZ] = acc[i];
}

// ---------------- launcher ----------------

extern "C" void kernel_launch(void* const* d_in, const int* in_sizes, int n_in,
                              void* d_out, int out_size, void* d_ws, size_t ws_size,
                              hipStream_t stream)
{
    const float* input = (const float*)d_in[0];
    const float* scale = (const float*)d_in[1];
    const int*   M_in  = (const int*)d_in[2];
    const int*   M     = (const int*)d_in[3];
    float*       out   = (float*)d_out;

    const int N = in_sizes[0] / IN_SZ;

    if (ws_size >= (size_t)(384 * 1024) && (N % BM) == 0) {
        float*          wf = (float*)d_ws;
        unsigned short* wb = (unsigned short*)((char*)d_ws + 256 * 1024);
        zero_kernel   <<<64,     256, 0, stream>>>(wf);
        scatter_kernel<<<8,      256, 0, stream>>>(scale, M_in, M, wf);
        cvt_kernel    <<<64,     256, 0, stream>>>(wf, wb);
        gemm_kernel   <<<N / BM, 512, 0, stream>>>(input, wb, out);
    } else {
        sparse_tp_kernel<<<(N + NB - 1) / NB, 256, 0, stream>>>(input, scale, M_in, M, out, N);
    }
}